// Round 1
// baseline (1166.822 us; speedup 1.0000x reference)
//
#include <hip/hip_runtime.h>
#include <math.h>

// Kernel 1: probs = sigmoid(pred); zero ax accumulator and output scalar.
__global__ void init_kernel(const float* __restrict__ pred,
                            float* __restrict__ probs,
                            float* __restrict__ ax,
                            float* __restrict__ out,
                            int n_vars, int n_constrs) {
    int i = blockIdx.x * blockDim.x + threadIdx.x;
    if (i < n_vars) {
        float x = pred[i];
        probs[i] = 1.0f / (1.0f + expf(-x));
    }
    if (i < n_constrs) ax[i] = 0.0f;
    if (i == 0) out[0] = 0.0f;
}

// Kernel 2: ax[constr_idx[k]] += coeff[k] * probs[var_idx[k]], 4 nnz per thread.
__global__ void scatter_kernel(const int* __restrict__ cidx,
                               const int* __restrict__ vidx,
                               const float* __restrict__ coeff,
                               const float* __restrict__ probs,
                               float* __restrict__ ax,
                               int nnz) {
    int i = blockIdx.x * blockDim.x + threadIdx.x;
    long long base = (long long)i * 4;
    if (base + 3 < (long long)nnz) {
        int4   c = ((const int4*)cidx)[i];
        int4   v = ((const int4*)vidx)[i];
        float4 w = ((const float4*)coeff)[i];
        atomicAdd(&ax[c.x], w.x * probs[v.x]);
        atomicAdd(&ax[c.y], w.y * probs[v.y]);
        atomicAdd(&ax[c.z], w.z * probs[v.z]);
        atomicAdd(&ax[c.w], w.w * probs[v.w]);
    } else if (base < (long long)nnz) {
        for (long long k = base; k < (long long)nnz; ++k) {
            atomicAdd(&ax[cidx[k]], coeff[k] * probs[vidx[k]]);
        }
    }
}

// Kernel 3: violation per constraint, block reduction, scaled atomic into out.
__global__ void reduce_kernel(const float* __restrict__ ax,
                              const float* __restrict__ rhs,
                              const int* __restrict__ sense,
                              float* __restrict__ out,
                              int n_constrs, float inv_n) {
    int i = blockIdx.x * blockDim.x + threadIdx.x;
    float v = 0.0f;
    if (i < n_constrs) {
        float d = ax[i] - rhs[i];
        int s = sense[i];
        v = (s == 1) ? fmaxf(d, 0.0f)
          : (s == 2) ? fmaxf(-d, 0.0f)
          : (s == 3) ? fabsf(d)
          : 0.0f;
    }
    // wave-64 reduction
    #pragma unroll
    for (int off = 32; off > 0; off >>= 1)
        v += __shfl_down(v, off, 64);

    __shared__ float wsum[4];  // 256 threads = 4 waves
    int lane = threadIdx.x & 63;
    int wid  = threadIdx.x >> 6;
    if (lane == 0) wsum[wid] = v;
    __syncthreads();
    if (threadIdx.x == 0) {
        float s = wsum[0] + wsum[1] + wsum[2] + wsum[3];
        atomicAdd(out, s * inv_n);
    }
}

extern "C" void kernel_launch(void* const* d_in, const int* in_sizes, int n_in,
                              void* d_out, int out_size, void* d_ws, size_t ws_size,
                              hipStream_t stream) {
    const float* pred  = (const float*)d_in[0];
    const int*   cidx  = (const int*)d_in[1];
    const int*   vidx  = (const int*)d_in[2];
    const float* coeff = (const float*)d_in[3];
    const float* rhs   = (const float*)d_in[4];
    const int*   sense = (const int*)d_in[5];

    const int n_vars    = in_sizes[0];
    const int nnz       = in_sizes[1];
    const int n_constrs = in_sizes[4];

    float* probs = (float*)d_ws;            // n_vars floats
    float* ax    = probs + n_vars;          // n_constrs floats
    float* out   = (float*)d_out;

    const int B = 256;

    // init: covers max(n_vars, n_constrs)
    int init_n = n_vars > n_constrs ? n_vars : n_constrs;
    init_kernel<<<(init_n + B - 1) / B, B, 0, stream>>>(
        pred, probs, ax, out, n_vars, n_constrs);

    // scatter: 4 nnz per thread
    int n_vec_threads = (nnz + 3) / 4;
    scatter_kernel<<<(n_vec_threads + B - 1) / B, B, 0, stream>>>(
        cidx, vidx, coeff, probs, ax, nnz);

    // reduce
    float inv_n = 1.0f / (float)n_constrs;
    reduce_kernel<<<(n_constrs + B - 1) / B, B, 0, stream>>>(
        ax, rhs, sense, out, n_constrs, inv_n);
}

// Round 2
// 1162.431 us; speedup vs baseline: 1.0038x; 1.0038x over previous
//
#include <hip/hip_runtime.h>
#include <math.h>

// Kernel 1: probs = sigmoid(pred); zero ax accumulator and output scalar.
__global__ void init_kernel(const float* __restrict__ pred,
                            float* __restrict__ probs,
                            float* __restrict__ ax,
                            float* __restrict__ out,
                            int n_vars, int n_constrs) {
    int i = blockIdx.x * blockDim.x + threadIdx.x;
    if (i < n_vars) {
        float x = pred[i];
        probs[i] = 1.0f / (1.0f + expf(-x));
    }
    if (i < n_constrs) ax[i] = 0.0f;
    if (i == 0) out[0] = 0.0f;
}

// Kernel 2: ax[constr_idx[k]] += coeff[k] * probs[var_idx[k]], 4 nnz per thread.
// unsafeAtomicAdd -> native global_atomic_add_f32 (no return, no CAS loop).
__global__ void scatter_kernel(const int* __restrict__ cidx,
                               const int* __restrict__ vidx,
                               const float* __restrict__ coeff,
                               const float* __restrict__ probs,
                               float* __restrict__ ax,
                               int nnz) {
    int i = blockIdx.x * blockDim.x + threadIdx.x;
    long long base = (long long)i * 4;
    if (base + 3 < (long long)nnz) {
        int4   c = ((const int4*)cidx)[i];
        int4   v = ((const int4*)vidx)[i];
        float4 w = ((const float4*)coeff)[i];
        float px = probs[v.x];
        float py = probs[v.y];
        float pz = probs[v.z];
        float pw = probs[v.w];
        unsafeAtomicAdd(&ax[c.x], w.x * px);
        unsafeAtomicAdd(&ax[c.y], w.y * py);
        unsafeAtomicAdd(&ax[c.z], w.z * pz);
        unsafeAtomicAdd(&ax[c.w], w.w * pw);
    } else if (base < (long long)nnz) {
        for (long long k = base; k < (long long)nnz; ++k) {
            unsafeAtomicAdd(&ax[cidx[k]], coeff[k] * probs[vidx[k]]);
        }
    }
}

// Kernel 3: violation per constraint, block reduction, scaled atomic into out.
__global__ void reduce_kernel(const float* __restrict__ ax,
                              const float* __restrict__ rhs,
                              const int* __restrict__ sense,
                              float* __restrict__ out,
                              int n_constrs, float inv_n) {
    int i = blockIdx.x * blockDim.x + threadIdx.x;
    float v = 0.0f;
    if (i < n_constrs) {
        float d = ax[i] - rhs[i];
        int s = sense[i];
        v = (s == 1) ? fmaxf(d, 0.0f)
          : (s == 2) ? fmaxf(-d, 0.0f)
          : (s == 3) ? fabsf(d)
          : 0.0f;
    }
    // wave-64 reduction
    #pragma unroll
    for (int off = 32; off > 0; off >>= 1)
        v += __shfl_down(v, off, 64);

    __shared__ float wsum[4];  // 256 threads = 4 waves
    int lane = threadIdx.x & 63;
    int wid  = threadIdx.x >> 6;
    if (lane == 0) wsum[wid] = v;
    __syncthreads();
    if (threadIdx.x == 0) {
        float s = wsum[0] + wsum[1] + wsum[2] + wsum[3];
        atomicAdd(out, s * inv_n);
    }
}

extern "C" void kernel_launch(void* const* d_in, const int* in_sizes, int n_in,
                              void* d_out, int out_size, void* d_ws, size_t ws_size,
                              hipStream_t stream) {
    const float* pred  = (const float*)d_in[0];
    const int*   cidx  = (const int*)d_in[1];
    const int*   vidx  = (const int*)d_in[2];
    const float* coeff = (const float*)d_in[3];
    const float* rhs   = (const float*)d_in[4];
    const int*   sense = (const int*)d_in[5];

    const int n_vars    = in_sizes[0];
    const int nnz       = in_sizes[1];
    const int n_constrs = in_sizes[4];

    float* probs = (float*)d_ws;            // n_vars floats
    float* ax    = probs + n_vars;          // n_constrs floats
    float* out   = (float*)d_out;

    const int B = 256;

    // init: covers max(n_vars, n_constrs)
    int init_n = n_vars > n_constrs ? n_vars : n_constrs;
    init_kernel<<<(init_n + B - 1) / B, B, 0, stream>>>(
        pred, probs, ax, out, n_vars, n_constrs);

    // scatter: 4 nnz per thread
    int n_vec_threads = (nnz + 3) / 4;
    scatter_kernel<<<(n_vec_threads + B - 1) / B, B, 0, stream>>>(
        cidx, vidx, coeff, probs, ax, nnz);

    // reduce
    float inv_n = 1.0f / (float)n_constrs;
    reduce_kernel<<<(n_constrs + B - 1) / B, B, 0, stream>>>(
        ax, rhs, sense, out, n_constrs, inv_n);
}

// Round 3
// 1160.824 us; speedup vs baseline: 1.0052x; 1.0014x over previous
//
#include <hip/hip_runtime.h>
#include <math.h>

#define NCOPY 8  // one ax copy per XCD

// Physical XCD id of the executing wave (HW_REG_XCC_ID = hwreg 20, offset 0, size 4).
__device__ __forceinline__ int xcc_id() {
    return __builtin_amdgcn_s_getreg(20 | (0 << 6) | ((4 - 1) << 11)) & (NCOPY - 1);
}

// L2-local fp32 atomic add: no sc0/sc1 bits -> executes in the issuing XCD's L2,
// NOT at the device-wide coherent point. Safe only because each ax copy is
// written exclusively by blocks on one XCD; dispatch-end L2 writeback publishes it.
__device__ __forceinline__ void atomic_add_f32_l2(float* p, float v) {
    asm volatile("global_atomic_add_f32 %0, %1, off" :: "v"(p), "v"(v) : "memory");
}

// Kernel 1: probs = sigmoid(pred); zero all NCOPY ax copies (float4) and out.
__global__ void init_kernel(const float* __restrict__ pred,
                            float* __restrict__ probs,
                            float4* __restrict__ ax4,   // NCOPY*n_constrs/4 float4s
                            float* __restrict__ out,
                            int n_vars, int n_zero4) {
    int i = blockIdx.x * blockDim.x + threadIdx.x;
    if (i < n_vars) {
        float x = pred[i];
        probs[i] = 1.0f / (1.0f + expf(-x));
    }
    if (i < n_zero4) ax4[i] = make_float4(0.f, 0.f, 0.f, 0.f);
    if (i == 0) out[0] = 0.0f;
}

// Kernel 2: ax_copy[xcc][constr_idx[k]] += coeff[k] * probs[var_idx[k]], 4 nnz/thread.
__global__ void scatter_kernel(const int* __restrict__ cidx,
                               const int* __restrict__ vidx,
                               const float* __restrict__ coeff,
                               const float* __restrict__ probs,
                               float* __restrict__ ax,
                               int nnz, int n_constrs) {
    float* axc = ax + (size_t)xcc_id() * (size_t)n_constrs;
    int i = blockIdx.x * blockDim.x + threadIdx.x;
    long long base = (long long)i * 4;
    if (base + 3 < (long long)nnz) {
        int4   c = ((const int4*)cidx)[i];
        int4   v = ((const int4*)vidx)[i];
        float4 w = ((const float4*)coeff)[i];
        float px = probs[v.x];
        float py = probs[v.y];
        float pz = probs[v.z];
        float pw = probs[v.w];
        atomic_add_f32_l2(&axc[c.x], w.x * px);
        atomic_add_f32_l2(&axc[c.y], w.y * py);
        atomic_add_f32_l2(&axc[c.z], w.z * pz);
        atomic_add_f32_l2(&axc[c.w], w.w * pw);
    } else if (base < (long long)nnz) {
        for (long long k = base; k < (long long)nnz; ++k) {
            atomic_add_f32_l2(&axc[cidx[k]], coeff[k] * probs[vidx[k]]);
        }
    }
}

// Kernel 3: sum the NCOPY copies, violation per constraint, block reduce, atomic out.
__global__ void reduce_kernel(const float* __restrict__ ax,
                              const float* __restrict__ rhs,
                              const int* __restrict__ sense,
                              float* __restrict__ out,
                              int n_constrs, float inv_n) {
    int i = blockIdx.x * blockDim.x + threadIdx.x;
    float v = 0.0f;
    if (i < n_constrs) {
        float a = 0.0f;
        #pragma unroll
        for (int c = 0; c < NCOPY; ++c)
            a += ax[(size_t)c * (size_t)n_constrs + i];
        float d = a - rhs[i];
        int s = sense[i];
        v = (s == 1) ? fmaxf(d, 0.0f)
          : (s == 2) ? fmaxf(-d, 0.0f)
          : (s == 3) ? fabsf(d)
          : 0.0f;
    }
    #pragma unroll
    for (int off = 32; off > 0; off >>= 1)
        v += __shfl_down(v, off, 64);

    __shared__ float wsum[4];
    int lane = threadIdx.x & 63;
    int wid  = threadIdx.x >> 6;
    if (lane == 0) wsum[wid] = v;
    __syncthreads();
    if (threadIdx.x == 0) {
        float s = wsum[0] + wsum[1] + wsum[2] + wsum[3];
        atomicAdd(out, s * inv_n);  // device-scope: cross-XCD correct
    }
}

extern "C" void kernel_launch(void* const* d_in, const int* in_sizes, int n_in,
                              void* d_out, int out_size, void* d_ws, size_t ws_size,
                              hipStream_t stream) {
    const float* pred  = (const float*)d_in[0];
    const int*   cidx  = (const int*)d_in[1];
    const int*   vidx  = (const int*)d_in[2];
    const float* coeff = (const float*)d_in[3];
    const float* rhs   = (const float*)d_in[4];
    const int*   sense = (const int*)d_in[5];

    const int n_vars    = in_sizes[0];
    const int nnz       = in_sizes[1];
    const int n_constrs = in_sizes[4];

    float* probs = (float*)d_ws;            // n_vars floats
    float* ax    = probs + n_vars;          // NCOPY * n_constrs floats
    float* out   = (float*)d_out;

    const int B = 256;

    // init: sigmoid over n_vars, zero NCOPY*n_constrs floats via float4
    int n_zero4 = (NCOPY * n_constrs) / 4;      // 4M/4 = 1M, divisible
    int init_n  = n_vars > n_zero4 ? n_vars : n_zero4;
    init_kernel<<<(init_n + B - 1) / B, B, 0, stream>>>(
        pred, probs, (float4*)ax, out, n_vars, n_zero4);

    // scatter: 4 nnz per thread
    int n_vec_threads = (nnz + 3) / 4;
    scatter_kernel<<<(n_vec_threads + B - 1) / B, B, 0, stream>>>(
        cidx, vidx, coeff, probs, ax, nnz, n_constrs);

    // reduce
    float inv_n = 1.0f / (float)n_constrs;
    reduce_kernel<<<(n_constrs + B - 1) / B, B, 0, stream>>>(
        ax, rhs, sense, out, n_constrs, inv_n);
}

// Round 4
// 570.743 us; speedup vs baseline: 2.0444x; 2.0339x over previous
//
#include <hip/hip_runtime.h>
#include <math.h>

#define R_LOG2 13
#define R_BKT  8192      // constraints per bucket (32 KB LDS accumulator)
#define SLICE  16        // blocks per bucket in accumulate phase
#define MAXNB  64        // max buckets supported by fast path

// ============================= fast path =============================

// probs = sigmoid(pred); zero bucket cursors and out.
__global__ void init_fast(const float* __restrict__ pred,
                          float* __restrict__ probs,
                          unsigned* __restrict__ cursor,
                          float* __restrict__ out,
                          int n_vars, int nb) {
    int i = blockIdx.x * blockDim.x + threadIdx.x;
    if (i < n_vars) probs[i] = 1.0f / (1.0f + expf(-pred[i]));
    if (i < nb) cursor[i] = 0;
    if (i == 0) out[0] = 0.0f;
}

// Phase 1: stream nnz, compute contributions, bin records by cidx>>13.
// Record: {lidx:16 | bf16(val):16}. Per-bucket streams reserved via one
// global atomicAdd per bucket per block (int atomics, low volume).
__global__ __launch_bounds__(256) void partition_kernel(
        const int* __restrict__ cidx, const int* __restrict__ vidx,
        const float* __restrict__ coeff, const float* __restrict__ probs,
        unsigned* __restrict__ cursor, unsigned* __restrict__ recs,
        int nnz4, int nb, unsigned cap) {
    __shared__ unsigned cnt[MAXNB];
    __shared__ unsigned gbase[MAXNB];
    const int tid = threadIdx.x;
    if (tid < nb) cnt[tid] = 0;
    __syncthreads();

    int   cs[16];
    float vs[16];
    bool  gv[4];
    #pragma unroll
    for (int g = 0; g < 4; ++g) {
        unsigned v = blockIdx.x * 1024u + g * 256u + (unsigned)tid;
        gv[g] = v < (unsigned)nnz4;
        if (gv[g]) {
            int4   c4 = ((const int4*)cidx)[v];
            int4   v4 = ((const int4*)vidx)[v];
            float4 w4 = ((const float4*)coeff)[v];
            cs[g*4+0] = c4.x; vs[g*4+0] = w4.x * probs[v4.x];
            cs[g*4+1] = c4.y; vs[g*4+1] = w4.y * probs[v4.y];
            cs[g*4+2] = c4.z; vs[g*4+2] = w4.z * probs[v4.z];
            cs[g*4+3] = c4.w; vs[g*4+3] = w4.w * probs[v4.w];
        }
    }

    // pass A: block histogram (LDS int atomics)
    #pragma unroll
    for (int g = 0; g < 4; ++g) if (gv[g]) {
        #pragma unroll
        for (int j = 0; j < 4; ++j)
            atomicAdd(&cnt[(unsigned)cs[g*4+j] >> R_LOG2], 1u);
    }
    __syncthreads();

    // reserve global space, reset running cursors
    if (tid < nb) {
        gbase[tid] = atomicAdd(&cursor[tid], cnt[tid]);
        cnt[tid] = 0;
    }
    __syncthreads();

    // pass B: write records into per-bucket streams
    #pragma unroll
    for (int g = 0; g < 4; ++g) if (gv[g]) {
        #pragma unroll
        for (int j = 0; j < 4; ++j) {
            int k = g*4 + j;
            unsigned b = (unsigned)cs[k] >> R_LOG2;
            unsigned slot = atomicAdd(&cnt[b], 1u);   // ds_add_rtn
            unsigned pos  = gbase[b] + slot;
            unsigned bits = __builtin_bit_cast(unsigned, vs[k]);
            bits += 0x7FFFu + ((bits >> 16) & 1u);    // RNE to bf16
            unsigned rec = ((unsigned)(cs[k] & (R_BKT - 1)) << 16) | (bits >> 16);
            if (pos < cap) recs[(size_t)b * cap + pos] = rec;
        }
    }
}

// Phase 2: block (b,s) accumulates slice s of bucket b into LDS, writes
// a per-slice partial copy (non-atomic streaming store).
__global__ __launch_bounds__(256) void accum_kernel(
        const unsigned* __restrict__ recs, const unsigned* __restrict__ cursor,
        float* __restrict__ partial, int n_constrs, unsigned cap) {
    __shared__ float acc[R_BKT];
    const int b = blockIdx.x / SLICE;
    const int s = blockIdx.x % SLICE;
    for (int j = threadIdx.x; j < R_BKT; j += blockDim.x) acc[j] = 0.0f;
    __syncthreads();

    unsigned cnt = cursor[b];
    if (cnt > cap) cnt = cap;
    unsigned start = (unsigned)(((unsigned long long)cnt * s) / SLICE);
    unsigned end   = (unsigned)(((unsigned long long)cnt * (s + 1)) / SLICE);
    const unsigned* base = recs + (size_t)b * cap;
    for (unsigned i = start + threadIdx.x; i < end; i += blockDim.x) {
        unsigned r = base[i];
        float v = __builtin_bit_cast(float, (r & 0xFFFFu) << 16);
        unsafeAtomicAdd(&acc[r >> 16], v);            // ds_add_f32
    }
    __syncthreads();

    const int gb = b * R_BKT;
    float* dst = partial + (size_t)s * n_constrs;
    for (int j = threadIdx.x * 4; j < R_BKT; j += blockDim.x * 4) {
        int g = gb + j;
        if (g < n_constrs) {
            float4 v4 = make_float4(acc[j], acc[j+1], acc[j+2], acc[j+3]);
            *(float4*)(dst + g) = v4;
        }
    }
}

// Phase 3: sum SLICE partials, violation by sense, mean.
__global__ void reduce_fast(const float* __restrict__ partial,
                            const float* __restrict__ rhs,
                            const int* __restrict__ sense,
                            float* __restrict__ out,
                            int n_constrs, float inv_n) {
    int i = blockIdx.x * blockDim.x + threadIdx.x;
    float v = 0.0f;
    if (i < n_constrs) {
        float a = 0.0f;
        #pragma unroll
        for (int s = 0; s < SLICE; ++s)
            a += partial[(size_t)s * n_constrs + i];
        float d = a - rhs[i];
        int sn = sense[i];
        v = (sn == 1) ? fmaxf(d, 0.0f)
          : (sn == 2) ? fmaxf(-d, 0.0f)
          : (sn == 3) ? fabsf(d)
          : 0.0f;
    }
    #pragma unroll
    for (int off = 32; off > 0; off >>= 1)
        v += __shfl_down(v, off, 64);
    __shared__ float wsum[4];
    int lane = threadIdx.x & 63;
    int wid  = threadIdx.x >> 6;
    if (lane == 0) wsum[wid] = v;
    __syncthreads();
    if (threadIdx.x == 0)
        atomicAdd(out, (wsum[0] + wsum[1] + wsum[2] + wsum[3]) * inv_n);
}

// ======================= fallback path (small ws) =======================

__global__ void init_kernel(const float* __restrict__ pred,
                            float* __restrict__ probs,
                            float* __restrict__ ax,
                            float* __restrict__ out,
                            int n_vars, int n_constrs) {
    int i = blockIdx.x * blockDim.x + threadIdx.x;
    if (i < n_vars) probs[i] = 1.0f / (1.0f + expf(-pred[i]));
    if (i < n_constrs) ax[i] = 0.0f;
    if (i == 0) out[0] = 0.0f;
}

__global__ void scatter_kernel(const int* __restrict__ cidx,
                               const int* __restrict__ vidx,
                               const float* __restrict__ coeff,
                               const float* __restrict__ probs,
                               float* __restrict__ ax,
                               int nnz) {
    int i = blockIdx.x * blockDim.x + threadIdx.x;
    long long base = (long long)i * 4;
    if (base + 3 < (long long)nnz) {
        int4   c = ((const int4*)cidx)[i];
        int4   v = ((const int4*)vidx)[i];
        float4 w = ((const float4*)coeff)[i];
        unsafeAtomicAdd(&ax[c.x], w.x * probs[v.x]);
        unsafeAtomicAdd(&ax[c.y], w.y * probs[v.y]);
        unsafeAtomicAdd(&ax[c.z], w.z * probs[v.z]);
        unsafeAtomicAdd(&ax[c.w], w.w * probs[v.w]);
    } else if (base < (long long)nnz) {
        for (long long k = base; k < (long long)nnz; ++k)
            unsafeAtomicAdd(&ax[cidx[k]], coeff[k] * probs[vidx[k]]);
    }
}

__global__ void reduce_kernel(const float* __restrict__ ax,
                              const float* __restrict__ rhs,
                              const int* __restrict__ sense,
                              float* __restrict__ out,
                              int n_constrs, float inv_n) {
    int i = blockIdx.x * blockDim.x + threadIdx.x;
    float v = 0.0f;
    if (i < n_constrs) {
        float d = ax[i] - rhs[i];
        int s = sense[i];
        v = (s == 1) ? fmaxf(d, 0.0f)
          : (s == 2) ? fmaxf(-d, 0.0f)
          : (s == 3) ? fabsf(d)
          : 0.0f;
    }
    #pragma unroll
    for (int off = 32; off > 0; off >>= 1)
        v += __shfl_down(v, off, 64);
    __shared__ float wsum[4];
    int lane = threadIdx.x & 63;
    int wid  = threadIdx.x >> 6;
    if (lane == 0) wsum[wid] = v;
    __syncthreads();
    if (threadIdx.x == 0)
        atomicAdd(out, (wsum[0] + wsum[1] + wsum[2] + wsum[3]) * inv_n);
}

// ============================== launch ==============================

static inline size_t align16(size_t x) { return (x + 15) & ~(size_t)15; }

extern "C" void kernel_launch(void* const* d_in, const int* in_sizes, int n_in,
                              void* d_out, int out_size, void* d_ws, size_t ws_size,
                              hipStream_t stream) {
    const float* pred  = (const float*)d_in[0];
    const int*   cidx  = (const int*)d_in[1];
    const int*   vidx  = (const int*)d_in[2];
    const float* coeff = (const float*)d_in[3];
    const float* rhs   = (const float*)d_in[4];
    const int*   sense = (const int*)d_in[5];

    const int n_vars    = in_sizes[0];
    const int nnz       = in_sizes[1];
    const int n_constrs = in_sizes[4];
    const int B = 256;
    const float inv_n = 1.0f / (float)n_constrs;

    const int nb = (n_constrs + R_BKT - 1) / R_BKT;
    unsigned cap = (unsigned)(((double)nnz * R_BKT / (double)n_constrs) * 1.0625) + 1024;

    // fast-path workspace layout
    size_t off_probs  = 0;
    size_t off_cursor = align16(off_probs + (size_t)n_vars * 4);
    size_t off_recs   = align16(off_cursor + (size_t)nb * 4);
    size_t off_part   = align16(off_recs + (size_t)nb * cap * 4);
    size_t need_fast  = off_part + (size_t)SLICE * n_constrs * 4;

    bool fast = (ws_size >= need_fast) && (nb <= MAXNB) && ((nnz & 3) == 0);

    if (fast) {
        float*    probs   = (float*)((char*)d_ws + off_probs);
        unsigned* cursor  = (unsigned*)((char*)d_ws + off_cursor);
        unsigned* recs    = (unsigned*)((char*)d_ws + off_recs);
        float*    partial = (float*)((char*)d_ws + off_part);
        float*    out     = (float*)d_out;

        int init_n = n_vars > nb ? n_vars : nb;
        init_fast<<<(init_n + B - 1) / B, B, 0, stream>>>(
            pred, probs, cursor, out, n_vars, nb);

        int nnz4 = nnz >> 2;                       // vec4 records
        int nblk1 = (nnz4 + 1023) / 1024;          // 1024 vec4s per block
        partition_kernel<<<nblk1, B, 0, stream>>>(
            cidx, vidx, coeff, probs, cursor, recs, nnz4, nb, cap);

        accum_kernel<<<nb * SLICE, B, 0, stream>>>(
            recs, cursor, partial, n_constrs, cap);

        reduce_fast<<<(n_constrs + B - 1) / B, B, 0, stream>>>(
            partial, rhs, sense, out, n_constrs, inv_n);
    } else {
        float* probs = (float*)d_ws;
        float* ax    = probs + n_vars;
        float* out   = (float*)d_out;

        int init_n = n_vars > n_constrs ? n_vars : n_constrs;
        init_kernel<<<(init_n + B - 1) / B, B, 0, stream>>>(
            pred, probs, ax, out, n_vars, n_constrs);

        int n_vec_threads = (nnz + 3) / 4;
        scatter_kernel<<<(n_vec_threads + B - 1) / B, B, 0, stream>>>(
            cidx, vidx, coeff, probs, ax, nnz);

        reduce_kernel<<<(n_constrs + B - 1) / B, B, 0, stream>>>(
            ax, rhs, sense, out, n_constrs, inv_n);
    }
}

// Round 5
// 512.213 us; speedup vs baseline: 2.2780x; 1.1143x over previous
//
#include <hip/hip_runtime.h>
#include <math.h>

#define R_LOG2 13
#define R_BKT  8192      // constraints per bucket (32 KB LDS accumulator)
#define SLICE  16        // blocks per bucket in accumulate phase
#define MAXNB  64        // max buckets supported by fast path
#define RECS_PER_BLK 4096

// ============================= fast path =============================

// probs = sigmoid(pred); zero bucket cursors and out.
__global__ void init_fast(const float* __restrict__ pred,
                          float* __restrict__ probs,
                          unsigned* __restrict__ cursor,
                          float* __restrict__ out,
                          int n_vars, int nb) {
    int i = blockIdx.x * blockDim.x + threadIdx.x;
    if (i < n_vars) probs[i] = 1.0f / (1.0f + expf(-pred[i]));
    if (i < nb) cursor[i] = 0;
    if (i == 0) out[0] = 0.0f;
}

// Phase 1: stream nnz, compute contributions, COUNTING-SORT the block's 4096
// records by bucket in LDS, then copy out each bucket segment contiguously
// (coalesced global writes instead of 20M scattered 4B stores).
// Record: {lidx:16 | bf16(val):16}.
__global__ __launch_bounds__(256) void partition_kernel(
        const int* __restrict__ cidx, const int* __restrict__ vidx,
        const float* __restrict__ coeff, const float* __restrict__ probs,
        unsigned* __restrict__ cursor, unsigned* __restrict__ recs,
        int nnz4, int nb, unsigned cap) {
    __shared__ unsigned hist[256];          // [b*4 + wave]
    __shared__ unsigned scan[256];          // inclusive prefix of hist
    __shared__ unsigned lcur[256];          // running cursor per (b,wave) segment
    __shared__ unsigned bstart[MAXNB + 1];  // bucket segment starts in sorted[]
    __shared__ unsigned gbase[MAXNB];       // reserved global base per bucket
    __shared__ unsigned sorted[RECS_PER_BLK];

    const int tid = threadIdx.x;
    const int sub = tid >> 6;               // wave id 0..3 (replication key)

    // ---- compute this thread's 16 records ----
    unsigned rw[16];   // packed record
    unsigned bk[16];   // bucket
    bool     gv[4];
    #pragma unroll
    for (int g = 0; g < 4; ++g) {
        unsigned v = blockIdx.x * 1024u + g * 256u + (unsigned)tid;
        gv[g] = v < (unsigned)nnz4;
        if (gv[g]) {
            int4   c4 = ((const int4*)cidx)[v];
            int4   v4 = ((const int4*)vidx)[v];
            float4 w4 = ((const float4*)coeff)[v];
            int   cc[4] = {c4.x, c4.y, c4.z, c4.w};
            float vv[4] = {w4.x * probs[v4.x], w4.y * probs[v4.y],
                           w4.z * probs[v4.z], w4.w * probs[v4.w]};
            #pragma unroll
            for (int j = 0; j < 4; ++j) {
                int k = g * 4 + j;
                unsigned bits = __builtin_bit_cast(unsigned, vv[j]);
                bits += 0x7FFFu + ((bits >> 16) & 1u);     // RNE to bf16
                rw[k] = ((unsigned)(cc[j] & (R_BKT - 1)) << 16) | (bits >> 16);
                bk[k] = (unsigned)cc[j] >> R_LOG2;
            }
        }
    }

    // ---- pass A: wave-replicated histogram ----
    hist[tid] = 0;
    __syncthreads();
    #pragma unroll
    for (int g = 0; g < 4; ++g) if (gv[g]) {
        #pragma unroll
        for (int j = 0; j < 4; ++j)
            atomicAdd(&hist[bk[g * 4 + j] * 4 + sub], 1u);
    }
    __syncthreads();

    // ---- inclusive scan over 256 counters (Hillis-Steele) ----
    scan[tid] = hist[tid];
    __syncthreads();
    #pragma unroll
    for (int d = 1; d < 256; d <<= 1) {
        unsigned t = (tid >= d) ? scan[tid - d] : 0u;
        __syncthreads();
        if (tid >= d) scan[tid] += t;
        __syncthreads();
    }

    // segment cursors (exclusive prefix), bucket starts, global reservation
    lcur[tid] = scan[tid] - hist[tid];
    if (tid < nb) bstart[tid] = scan[tid * 4] - hist[tid * 4];
    if (tid == 0) bstart[nb] = scan[255];
    __syncthreads();
    if (tid < nb) {
        unsigned cnt = bstart[tid + 1] - bstart[tid];
        gbase[tid] = cnt ? atomicAdd(&cursor[tid], cnt) : 0u;
    }
    __syncthreads();

    // ---- pass B: scatter into sorted LDS array ----
    #pragma unroll
    for (int g = 0; g < 4; ++g) if (gv[g]) {
        #pragma unroll
        for (int j = 0; j < 4; ++j) {
            int k = g * 4 + j;
            unsigned lpos = atomicAdd(&lcur[bk[k] * 4 + sub], 1u);
            sorted[lpos] = rw[k];
        }
    }
    __syncthreads();

    // ---- pass C: coalesced copy-out, bucket segments contiguous ----
    unsigned total = bstart[nb];
    for (unsigned p = tid; p < total; p += 256u) {
        // binary search: largest b with bstart[b] <= p
        unsigned lo = 0, hi = (unsigned)nb - 1;
        while (lo < hi) {
            unsigned mid = (lo + hi + 1) >> 1;
            if (bstart[mid] <= p) lo = mid; else hi = mid - 1;
        }
        unsigned pos = gbase[lo] + (p - bstart[lo]);
        if (pos < cap) recs[(size_t)lo * cap + pos] = sorted[p];
    }
}

// Phase 2: block (b,s) accumulates slice s of bucket b into LDS, writes
// a per-slice partial copy (non-atomic streaming store).
__global__ __launch_bounds__(256) void accum_kernel(
        const unsigned* __restrict__ recs, const unsigned* __restrict__ cursor,
        float* __restrict__ partial, int n_constrs, unsigned cap) {
    __shared__ float acc[R_BKT];
    const int b = blockIdx.x / SLICE;
    const int s = blockIdx.x % SLICE;
    for (int j = threadIdx.x; j < R_BKT; j += blockDim.x) acc[j] = 0.0f;
    __syncthreads();

    unsigned cnt = cursor[b];
    if (cnt > cap) cnt = cap;
    unsigned start = (unsigned)(((unsigned long long)cnt * s) / SLICE);
    unsigned end   = (unsigned)(((unsigned long long)cnt * (s + 1)) / SLICE);
    const unsigned* base = recs + (size_t)b * cap;
    for (unsigned i = start + threadIdx.x; i < end; i += blockDim.x) {
        unsigned r = base[i];
        float v = __builtin_bit_cast(float, (r & 0xFFFFu) << 16);
        unsafeAtomicAdd(&acc[r >> 16], v);            // ds_add_f32
    }
    __syncthreads();

    const int gb = b * R_BKT;
    float* dst = partial + (size_t)s * n_constrs;
    for (int j = threadIdx.x * 4; j < R_BKT; j += blockDim.x * 4) {
        int g = gb + j;
        if (g < n_constrs) {
            float4 v4 = make_float4(acc[j], acc[j+1], acc[j+2], acc[j+3]);
            *(float4*)(dst + g) = v4;
        }
    }
}

// Phase 3: sum SLICE partials, violation by sense, mean.
__global__ void reduce_fast(const float* __restrict__ partial,
                            const float* __restrict__ rhs,
                            const int* __restrict__ sense,
                            float* __restrict__ out,
                            int n_constrs, float inv_n) {
    int i = blockIdx.x * blockDim.x + threadIdx.x;
    float v = 0.0f;
    if (i < n_constrs) {
        float a = 0.0f;
        #pragma unroll
        for (int s = 0; s < SLICE; ++s)
            a += partial[(size_t)s * n_constrs + i];
        float d = a - rhs[i];
        int sn = sense[i];
        v = (sn == 1) ? fmaxf(d, 0.0f)
          : (sn == 2) ? fmaxf(-d, 0.0f)
          : (sn == 3) ? fabsf(d)
          : 0.0f;
    }
    #pragma unroll
    for (int off = 32; off > 0; off >>= 1)
        v += __shfl_down(v, off, 64);
    __shared__ float wsum[4];
    int lane = threadIdx.x & 63;
    int wid  = threadIdx.x >> 6;
    if (lane == 0) wsum[wid] = v;
    __syncthreads();
    if (threadIdx.x == 0)
        atomicAdd(out, (wsum[0] + wsum[1] + wsum[2] + wsum[3]) * inv_n);
}

// ======================= fallback path (small ws) =======================

__global__ void init_kernel(const float* __restrict__ pred,
                            float* __restrict__ probs,
                            float* __restrict__ ax,
                            float* __restrict__ out,
                            int n_vars, int n_constrs) {
    int i = blockIdx.x * blockDim.x + threadIdx.x;
    if (i < n_vars) probs[i] = 1.0f / (1.0f + expf(-pred[i]));
    if (i < n_constrs) ax[i] = 0.0f;
    if (i == 0) out[0] = 0.0f;
}

__global__ void scatter_kernel(const int* __restrict__ cidx,
                               const int* __restrict__ vidx,
                               const float* __restrict__ coeff,
                               const float* __restrict__ probs,
                               float* __restrict__ ax,
                               int nnz) {
    int i = blockIdx.x * blockDim.x + threadIdx.x;
    long long base = (long long)i * 4;
    if (base + 3 < (long long)nnz) {
        int4   c = ((const int4*)cidx)[i];
        int4   v = ((const int4*)vidx)[i];
        float4 w = ((const float4*)coeff)[i];
        unsafeAtomicAdd(&ax[c.x], w.x * probs[v.x]);
        unsafeAtomicAdd(&ax[c.y], w.y * probs[v.y]);
        unsafeAtomicAdd(&ax[c.z], w.z * probs[v.z]);
        unsafeAtomicAdd(&ax[c.w], w.w * probs[v.w]);
    } else if (base < (long long)nnz) {
        for (long long k = base; k < (long long)nnz; ++k)
            unsafeAtomicAdd(&ax[cidx[k]], coeff[k] * probs[vidx[k]]);
    }
}

__global__ void reduce_kernel(const float* __restrict__ ax,
                              const float* __restrict__ rhs,
                              const int* __restrict__ sense,
                              float* __restrict__ out,
                              int n_constrs, float inv_n) {
    int i = blockIdx.x * blockDim.x + threadIdx.x;
    float v = 0.0f;
    if (i < n_constrs) {
        float d = ax[i] - rhs[i];
        int s = sense[i];
        v = (s == 1) ? fmaxf(d, 0.0f)
          : (s == 2) ? fmaxf(-d, 0.0f)
          : (s == 3) ? fabsf(d)
          : 0.0f;
    }
    #pragma unroll
    for (int off = 32; off > 0; off >>= 1)
        v += __shfl_down(v, off, 64);
    __shared__ float wsum[4];
    int lane = threadIdx.x & 63;
    int wid  = threadIdx.x >> 6;
    if (lane == 0) wsum[wid] = v;
    __syncthreads();
    if (threadIdx.x == 0)
        atomicAdd(out, (wsum[0] + wsum[1] + wsum[2] + wsum[3]) * inv_n);
}

// ============================== launch ==============================

static inline size_t align16(size_t x) { return (x + 15) & ~(size_t)15; }

extern "C" void kernel_launch(void* const* d_in, const int* in_sizes, int n_in,
                              void* d_out, int out_size, void* d_ws, size_t ws_size,
                              hipStream_t stream) {
    const float* pred  = (const float*)d_in[0];
    const int*   cidx  = (const int*)d_in[1];
    const int*   vidx  = (const int*)d_in[2];
    const float* coeff = (const float*)d_in[3];
    const float* rhs   = (const float*)d_in[4];
    const int*   sense = (const int*)d_in[5];

    const int n_vars    = in_sizes[0];
    const int nnz       = in_sizes[1];
    const int n_constrs = in_sizes[4];
    const int B = 256;
    const float inv_n = 1.0f / (float)n_constrs;

    const int nb = (n_constrs + R_BKT - 1) / R_BKT;
    unsigned cap = (unsigned)(((double)nnz * R_BKT / (double)n_constrs) * 1.0625) + 1024;

    // fast-path workspace layout
    size_t off_probs  = 0;
    size_t off_cursor = align16(off_probs + (size_t)n_vars * 4);
    size_t off_recs   = align16(off_cursor + (size_t)nb * 4);
    size_t off_part   = align16(off_recs + (size_t)nb * cap * 4);
    size_t need_fast  = off_part + (size_t)SLICE * n_constrs * 4;

    bool fast = (ws_size >= need_fast) && (nb <= MAXNB) && ((nnz & 3) == 0);

    if (fast) {
        float*    probs   = (float*)((char*)d_ws + off_probs);
        unsigned* cursor  = (unsigned*)((char*)d_ws + off_cursor);
        unsigned* recs    = (unsigned*)((char*)d_ws + off_recs);
        float*    partial = (float*)((char*)d_ws + off_part);
        float*    out     = (float*)d_out;

        int init_n = n_vars > nb ? n_vars : nb;
        init_fast<<<(init_n + B - 1) / B, B, 0, stream>>>(
            pred, probs, cursor, out, n_vars, nb);

        int nnz4 = nnz >> 2;
        int nblk1 = (nnz4 + 1023) / 1024;          // 4096 records per block
        partition_kernel<<<nblk1, B, 0, stream>>>(
            cidx, vidx, coeff, probs, cursor, recs, nnz4, nb, cap);

        accum_kernel<<<nb * SLICE, B, 0, stream>>>(
            recs, cursor, partial, n_constrs, cap);

        reduce_fast<<<(n_constrs + B - 1) / B, B, 0, stream>>>(
            partial, rhs, sense, out, n_constrs, inv_n);
    } else {
        float* probs = (float*)d_ws;
        float* ax    = probs + n_vars;
        float* out   = (float*)d_out;

        int init_n = n_vars > n_constrs ? n_vars : n_constrs;
        init_kernel<<<(init_n + B - 1) / B, B, 0, stream>>>(
            pred, probs, ax, out, n_vars, n_constrs);

        int n_vec_threads = (nnz + 3) / 4;
        scatter_kernel<<<(n_vec_threads + B - 1) / B, B, 0, stream>>>(
            cidx, vidx, coeff, probs, ax, nnz);

        reduce_kernel<<<(n_constrs + B - 1) / B, B, 0, stream>>>(
            ax, rhs, sense, out, n_constrs, inv_n);
    }
}